// Round 1
// baseline (54.793 us; speedup 1.0000x reference)
//
#include <hip/hip_runtime.h>

// SoftHistLoss: x,y [16,3,512,512] f32 -> scalar f32
// hist_i = sum_px [ sigma(150(v-e_i)) - sigma(150(v-e_{i+1})) ], e_j = j/10.
// Pixel in bin k=floor(10v) contributes (1-a) to bin k-1, (a-b) to bin k, b to bin k+1,
// a = sigma(150(v-e_k)), b = sigma(150(v-e_{k+1})). Dropped tails < 3.1e-7/pixel.

static constexpr int PLANES_PER_IMG = 48;          // 16*3
static constexpr int PLANE_PX  = 512 * 512;        // 262144
static constexpr int SPP       = 32;               // sub-blocks per plane
static constexpr int THREADS   = 256;
static constexpr int CHUNK     = PLANE_PX / SPP;   // 8192 px per block
static constexpr int ROW       = 44;               // padded floats/thread (10*4 + 4), 16B-aligned stride
static constexpr int NCOL      = 40;               // 10 bins * 4 (U,V,W,pad)

__global__ __launch_bounds__(THREADS) void soft_hist_partial(
    const float* __restrict__ xin, const float* __restrict__ yin,
    float* __restrict__ G /* [96][NCOL] */)
{
  __shared__ __align__(16) float ws[THREADS * ROW];  // 45056 B -> 3 blocks/CU
  const int t = threadIdx.x;
  for (int i = t; i < THREADS * ROW; i += THREADS) ws[i] = 0.0f;
  __syncthreads();

  const int blk   = blockIdx.x;
  const int plane = blk / SPP;                       // 0..95 (0..47 = x, 48..95 = y)
  const int sub   = blk - plane * SPP;
  const float* src = (plane < PLANES_PER_IMG ? xin : yin)
                   + (size_t)(plane % PLANES_PER_IMG) * PLANE_PX
                   + (size_t)sub * CHUNK;

  float* my = ws + t * ROW;
  const float4* src4 = (const float4*)src;

  constexpr int ITERS = CHUNK / (THREADS * 4);       // 8
  #pragma unroll
  for (int it = 0; it < ITERS; ++it) {
    float4 v4 = src4[it * THREADS + t];
    float vv[4] = {v4.x, v4.y, v4.z, v4.w};
    #pragma unroll
    for (int j = 0; j < 4; ++j) {
      float v  = vv[j];
      float kf = floorf(v * 10.0f);
      kf = fminf(fmaxf(kf, 0.0f), 9.0f);
      int   k  = (int)kf;
      float xx = fmaf(-15.0f, kf, 150.0f * v);       // 150(v - e_k), in [0,15]
      float ex = __expf(-xx);                         // exp(-x)
      float ey = ex * 3269017.3724721107f;            // exp(15-x) = exp(-(x-15))
      float a  = __builtin_amdgcn_rcpf(1.0f + ex);    // sigma(x)
      float b  = __builtin_amdgcn_rcpf(1.0f + ey);    // sigma(x-15)
      float4* slot = (float4*)(my + (k << 2));
      float4 o = *slot;
      o.x += a - b;      // U -> bin k
      o.y += b;          // V -> bin k+1
      o.z += 1.0f - a;   // W -> bin k-1
      *slot = o;
    }
  }
  __syncthreads();

  // reduce 256 thread-rows for the 40 columns; columns map t = 4*bin + comp
  if (t < NCOL) {
    const int c = t & 3;
    if (c < 3) {
      float s = 0.0f;
      #pragma unroll 8
      for (int r = 0; r < THREADS; ++r) s += ws[r * ROW + t];
      atomicAdd(&G[plane * NCOL + t], s);
    }
  }
}

__global__ __launch_bounds__(512) void soft_hist_loss(
    const float* __restrict__ G, float* __restrict__ out)
{
  __shared__ float red[512];
  const int t = threadIdx.x;
  float val = 0.0f;
  if (t < 480) {
    const int pc = t / 10;        // (b,c) pair 0..47
    const int i  = t - pc * 10;   // bin 0..9
    const float* gx = G + pc * NCOL;
    const float* gy = G + (pc + PLANES_PER_IMG) * NCOL;
    float hx = gx[4 * i]
             + (i > 0 ? gx[4 * (i - 1) + 1] : 0.0f)
             + (i < 9 ? gx[4 * (i + 1) + 2] : 0.0f);
    float hy = gy[4 * i]
             + (i > 0 ? gy[4 * (i - 1) + 1] : 0.0f)
             + (i < 9 ? gy[4 * (i + 1) + 2] : 0.0f);
    val = fabsf(hx - hy);
  }
  red[t] = val;
  __syncthreads();
  for (int s = 256; s > 0; s >>= 1) {
    if (t < s) red[t] += red[t + s];
    __syncthreads();
  }
  // loss = sum * (1/10) * (1/16) * 1e-4
  if (t == 0) out[0] = red[0] * 6.25e-7f;
}

extern "C" void kernel_launch(void* const* d_in, const int* in_sizes, int n_in,
                              void* d_out, int out_size, void* d_ws, size_t ws_size,
                              hipStream_t stream) {
  const float* x = (const float*)d_in[0];
  const float* y = (const float*)d_in[1];
  float* G = (float*)d_ws;                     // 96*40*4 = 15360 B
  hipMemsetAsync(d_ws, 0, 96 * NCOL * sizeof(float), stream);
  soft_hist_partial<<<96 * SPP, THREADS, 0, stream>>>(x, y, G);
  soft_hist_loss<<<1, 512, 0, stream>>>(G, (float*)d_out);
}